// Round 18
// baseline (187.963 us; speedup 1.0000x reference)
//
#include <hip/hip_runtime.h>
#include <hip/hip_cooperative_groups.h>

namespace cg = cooperative_groups;

#define NN 50000
#define NE 100000
#define NREL 64
#define D 64
#define RCAP 1280      // per-relation bucket capacity (expected ~676)
#define SCAP 8192      // self-only bucket capacity (expected ~6766)
#define CSTR 16        // cursor stride in ints (64 B per counter)
#define BR   7         // rel blocks per relation (448) + 64 self = 512 = grid
#define GRID 512
#define FILL_ITERS 2   // 128 fill blocks * 256 * 2 = 65536 >= NN

typedef unsigned long long u64;
using f16x8 = __attribute__((ext_vector_type(8))) _Float16;
using f32x4 = __attribute__((ext_vector_type(4))) float;

// ws layout (bytes):
// packed @0 (400KB) | cursor @400K | rbucket @408K (327.7KB) | sbucket @736K (32KB) |
// h2 @768K (6.4MB) | wsT @7168K (8KB) | w16T @7176K (512KB)
#define WS_CURSOR  (400 * 1024)
#define WS_RBUCKET (408 * 1024)
#define WS_SBUCKET (736 * 1024)
#define WS_H2      (768 * 1024)
#define WS_WST     (7168 * 1024)
#define WS_W16T    (7176 * 1024)

struct H4 { _Float16 v[4]; };

__global__ __launch_bounds__(256, 2) void k_mega(
    const int* __restrict__ edges, const float* __restrict__ h,
    const float* __restrict__ weight, const float* __restrict__ wself,
    u64* __restrict__ packed, int* __restrict__ cursor,
    unsigned* __restrict__ rbucket, unsigned* __restrict__ sbucket,
    _Float16* __restrict__ h2, _Float16* __restrict__ w16T,
    _Float16* __restrict__ wsT, float* __restrict__ out)
{
    cg::grid_group grid = cg::this_grid();

    __shared__ _Float16 tile[D * D];   // 8 KiB (P1 transpose)
    __shared__ int hcnt[65];
    __shared__ int hbase[65];

    const int b = blockIdx.x;
    const int t = threadIdx.x;
    const int gt = b * 256 + t;
    const int nthr = GRID * 256;

    // ---------- P0: zero packed + cursor ----------
    for (int i = gt; i < NN; i += nthr) packed[i] = 0ull;
    if (gt < 65) cursor[gt * CSTR] = 0;
    grid.sync();

    // ---------- P1: scatter | weight transpose->f16 | h convert->f16 ----------
    if (b < 64) {
        // edge scatter: key = (e+1)<<22 | rel<<16 | src
        for (int e = b * 256 + t; e < NE; e += 64 * 256) {
            const int s = edges[e * 3 + 0];
            const int r = edges[e * 3 + 1];
            const int d = edges[e * 3 + 2];
            const u64 key = ((u64)(e + 1) << 22) | ((u64)r << 16) | (u64)s;
            atomicMax(&packed[d], key);
        }
    } else if (b < 129) {
        // transpose one matrix: tile[n][k] = (f16)W[k][n], coalesced write-out
        const int r = b - 64;                       // 0..63 rel, 64 = wself
        const float4* __restrict__ src4 = reinterpret_cast<const float4*>(
            (r < NREL) ? (weight + (size_t)r * D * D) : wself);
        #pragma unroll
        for (int it = 0; it < 4; ++it) {
            const int idx = it * 256 + t;           // float4 idx 0..1023
            const float4 w = src4[idx];
            const int k  = idx >> 4;
            const int n0 = (idx & 15) << 2;
            tile[(n0 + 0) * D + k] = (_Float16)w.x;
            tile[(n0 + 1) * D + k] = (_Float16)w.y;
            tile[(n0 + 2) * D + k] = (_Float16)w.z;
            tile[(n0 + 3) * D + k] = (_Float16)w.w;
        }
        __syncthreads();
        f16x8* __restrict__ dst = reinterpret_cast<f16x8*>(
            (r < NREL) ? (w16T + ((size_t)r << 12)) : wsT);
        const f16x8* __restrict__ src = reinterpret_cast<const f16x8*>(tile);
        #pragma unroll
        for (int it = 0; it < 2; ++it)
            dst[it * 256 + t] = src[it * 256 + t];
    } else {
        // h convert: 383 blocks, coalesced f32x4 -> f16x4
        const int ct = (b - 129) * 256 + t;
        const int cn = (GRID - 129) * 256;
        const float4* __restrict__ hf4 = reinterpret_cast<const float4*>(h);
        H4* __restrict__ o4 = reinterpret_cast<H4*>(h2);
        for (int m = ct; m < NN * (D / 4); m += cn) {
            const float4 p = hf4[m];
            H4 o;
            o.v[0] = (_Float16)p.x; o.v[1] = (_Float16)p.y;
            o.v[2] = (_Float16)p.z; o.v[3] = (_Float16)p.w;
            o4[m] = o;
        }
    }
    grid.sync();

    // ---------- P2: bucket fill (blocks 0..127) ----------
    if (b < 128) {
        if (t < 65) hcnt[t] = 0;
        __syncthreads();

        int      myr[FILL_ITERS];
        int      myslot[FILL_ITERS];
        unsigned myent[FILL_ITERS];

        #pragma unroll
        for (int it = 0; it < FILL_ITERS; ++it) {
            const int v = (b * FILL_ITERS + it) * 256 + t;
            myr[it] = -1;
            if (v < NN) {
                const u64 key = packed[v];
                if (key) {
                    myr[it]   = (int)((key >> 16) & 63);
                    myent[it] = ((unsigned)v << 16) | (unsigned)(key & 0xFFFF);
                } else {
                    myr[it]   = 64;
                    myent[it] = (unsigned)v;
                }
                myslot[it] = atomicAdd(&hcnt[myr[it]], 1);
            }
        }
        __syncthreads();
        if (t < 65 && hcnt[t] > 0)
            hbase[t] = atomicAdd(&cursor[t * CSTR], hcnt[t]);
        __syncthreads();

        #pragma unroll
        for (int it = 0; it < FILL_ITERS; ++it) {
            const int r = myr[it];
            if (r >= 0) {
                const int p = hbase[r] + myslot[it];
                if (r < 64) { if (p < RCAP) rbucket[r * RCAP + p] = myent[it]; }
                else        { if (p < SCAP) sbucket[p] = myent[it]; }
            }
        }
    }
    grid.sync();

    // ---------- P3: MFMA compute (A = W^T frags, B = gathered h rows) ----------
    const int lane = t & 63;
    const int wv   = t >> 6;
    const bool isRel = b < NREL * BR;

    int r = 64, wslot, wstride, cnt;
    const unsigned* __restrict__ seg;
    if (isRel) {
        r = b / BR;
        wslot = (b % BR) * 4 + wv;
        wstride = BR * 4;
        seg = rbucket + r * RCAP;
        cnt = min(cursor[r * CSTR], RCAP);
    } else {
        wslot = (b - NREL * BR) * 4 + wv;
        wstride = 64 * 4;
        seg = sbucket;
        cnt = min(cursor[64 * CSTR], SCAP);
    }
    if (cnt == 0 || wslot * 16 >= cnt) return;

    const int kbase = (lane >> 4) * 8;
    const int ncol  = lane & 15;            // A-row m (output-dim sub) / B-col n (node)

    f16x8 was[4][2];
    #pragma unroll
    for (int nt = 0; nt < 4; ++nt)
        #pragma unroll
        for (int ks = 0; ks < 2; ++ks)
            was[nt][ks] = *reinterpret_cast<const f16x8*>(
                wsT + (size_t)(nt * 16 + ncol) * D + ks * 32 + kbase);

    f16x8 wa[4][2];
    if (isRel) {
        const _Float16* __restrict__ wr = w16T + ((size_t)r << 12);
        #pragma unroll
        for (int nt = 0; nt < 4; ++nt)
            #pragma unroll
            for (int ks = 0; ks < 2; ++ks)
                wa[nt][ks] = *reinterpret_cast<const f16x8*>(
                    wr + (size_t)(nt * 16 + ncol) * D + ks * 32 + kbase);
    }

    for (int tt = wslot; tt * 16 < cnt; tt += wstride) {
        const unsigned ent = seg[min(tt * 16 + ncol, cnt - 1)];  // this lane's node
        const int v = isRel ? (int)(ent >> 16) : (int)ent;
        const int s = (int)(ent & 0xFFFF);

        f32x4 c[4];
        #pragma unroll
        for (int nt = 0; nt < 4; ++nt) c[nt] = (f32x4){0.f, 0.f, 0.f, 0.f};

        {   // self part: B = h2[v]
            const f16x8 b0 = *reinterpret_cast<const f16x8*>(h2 + (size_t)v * D + kbase);
            const f16x8 b1 = *reinterpret_cast<const f16x8*>(h2 + (size_t)v * D + 32 + kbase);
            #pragma unroll
            for (int nt = 0; nt < 4; ++nt) {
                c[nt] = __builtin_amdgcn_mfma_f32_16x16x32_f16(was[nt][0], b0, c[nt], 0, 0, 0);
                c[nt] = __builtin_amdgcn_mfma_f32_16x16x32_f16(was[nt][1], b1, c[nt], 0, 0, 0);
            }
        }
        if (isRel) {   // rel part: B = h2[s]
            const f16x8 b0 = *reinterpret_cast<const f16x8*>(h2 + (size_t)s * D + kbase);
            const f16x8 b1 = *reinterpret_cast<const f16x8*>(h2 + (size_t)s * D + 32 + kbase);
            #pragma unroll
            for (int nt = 0; nt < 4; ++nt) {
                c[nt] = __builtin_amdgcn_mfma_f32_16x16x32_f16(wa[nt][0], b0, c[nt], 0, 0, 0);
                c[nt] = __builtin_amdgcn_mfma_f32_16x16x32_f16(wa[nt][1], b1, c[nt], 0, 0, 0);
            }
        }

        // store: lane's node v, output dims o = nt*16 + (lane>>4)*4 + q
        float* __restrict__ orow = out + (size_t)v * D + (lane >> 4) * 4;
        #pragma unroll
        for (int nt = 0; nt < 4; ++nt)
            *reinterpret_cast<float4*>(orow + nt * 16) =
                make_float4(c[nt][0], c[nt][1], c[nt][2], c[nt][3]);
    }
}

extern "C" void kernel_launch(void* const* d_in, const int* in_sizes, int n_in,
                              void* d_out, int out_size, void* d_ws, size_t ws_size,
                              hipStream_t stream) {
    const int*   edges  = (const int*)d_in[1];
    const float* h      = (const float*)d_in[0];
    const float* weight = (const float*)d_in[2];
    const float* wself  = (const float*)d_in[3];
    float* out = (float*)d_out;

    char* ws = (char*)d_ws;
    u64*      packed  = (u64*)ws;
    int*      cursor  = (int*)(ws + WS_CURSOR);
    unsigned* rbucket = (unsigned*)(ws + WS_RBUCKET);
    unsigned* sbucket = (unsigned*)(ws + WS_SBUCKET);
    _Float16* h2      = (_Float16*)(ws + WS_H2);
    _Float16* wsT     = (_Float16*)(ws + WS_WST);
    _Float16* w16T    = (_Float16*)(ws + WS_W16T);

    void* args[] = { (void*)&edges, (void*)&h, (void*)&weight, (void*)&wself,
                     (void*)&packed, (void*)&cursor, (void*)&rbucket, (void*)&sbucket,
                     (void*)&h2, (void*)&w16T, (void*)&wsT, (void*)&out };

    hipLaunchCooperativeKernel((const void*)k_mega, dim3(GRID), dim3(256),
                               args, 0, stream);
}

// Round 19
// 35.426 us; speedup vs baseline: 5.3058x; 5.3058x over previous
//
#include <hip/hip_runtime.h>

#define NN 50000
#define NE 100000
#define NREL 64
#define D 64
#define RCAP 1280      // per-relation bucket capacity (expected ~676)
#define SCAP 8192      // self-only bucket capacity (expected ~6766)
#define CSTR 16        // cursor stride in ints (64 B per counter)
#define BR   8         // rel blocks per relation
#define SBLK 64        // self-only blocks
#define FILL_BLOCKS 128
#define FILL_ITERS  2
#define PRE_BLOCKS 512

typedef unsigned long long u64;
using f16x8 = __attribute__((ext_vector_type(8))) _Float16;
using f32x4 = __attribute__((ext_vector_type(4))) float;

// ws layout (bytes):
// packed @0 (400KB) | cursor @400K | rbucket @408K (327.7KB) | sbucket @736K (32KB) |
// h2 @768K (6.4MB) | wsT @7168K (8KB) | w16T @7176K (512KB)
#define WS_CURSOR  (400 * 1024)
#define WS_RBUCKET (408 * 1024)
#define WS_SBUCKET (736 * 1024)
#define WS_H2      (768 * 1024)
#define WS_WST     (7168 * 1024)
#define WS_W16T    (7176 * 1024)

struct H4 { _Float16 v[4]; };

// zero packed/cursor + h->f16 (all blocks) + weight transpose->f16 (blocks 0..64,
// LDS tile, coalesced writes)
__global__ __launch_bounds__(256) void k_pre(
    const float* __restrict__ h, const float* __restrict__ weight,
    const float* __restrict__ wself, u64* __restrict__ packed,
    int* __restrict__ cursor, _Float16* __restrict__ h2,
    _Float16* __restrict__ w16T, _Float16* __restrict__ wsT)
{
    __shared__ _Float16 tile[D * D];   // 8 KiB

    const int b = blockIdx.x;
    const int t = threadIdx.x;
    const int gt = b * 256 + t;
    const int nthr = PRE_BLOCKS * 256;

    for (int i = gt; i < NN; i += nthr) packed[i] = 0ull;
    if (gt < 65) cursor[gt * CSTR] = 0;

    // weight transpose (blocks 0..64): tile[n][k] = (f16)W[k][n], coalesced out
    if (b < 65) {
        const float4* __restrict__ src4 = reinterpret_cast<const float4*>(
            (b < NREL) ? (weight + (size_t)b * D * D) : wself);
        #pragma unroll
        for (int it = 0; it < 4; ++it) {
            const int idx = it * 256 + t;           // float4 idx 0..1023
            const float4 w = src4[idx];
            const int k  = idx >> 4;
            const int n0 = (idx & 15) << 2;
            tile[(n0 + 0) * D + k] = (_Float16)w.x;
            tile[(n0 + 1) * D + k] = (_Float16)w.y;
            tile[(n0 + 2) * D + k] = (_Float16)w.z;
            tile[(n0 + 3) * D + k] = (_Float16)w.w;
        }
        __syncthreads();
        f16x8* __restrict__ dst = reinterpret_cast<f16x8*>(
            (b < NREL) ? (w16T + ((size_t)b << 12)) : wsT);
        const f16x8* __restrict__ src = reinterpret_cast<const f16x8*>(tile);
        #pragma unroll
        for (int it = 0; it < 2; ++it)
            dst[it * 256 + t] = src[it * 256 + t];
    }

    // h convert: all blocks, coalesced f32x4 -> f16x4
    const float4* __restrict__ hf4 = reinterpret_cast<const float4*>(h);
    H4* __restrict__ o4 = reinterpret_cast<H4*>(h2);
    for (int m = gt; m < NN * (D / 4); m += nthr) {
        const float4 p = hf4[m];
        H4 o;
        o.v[0] = (_Float16)p.x; o.v[1] = (_Float16)p.y;
        o.v[2] = (_Float16)p.z; o.v[3] = (_Float16)p.w;
        o4[m] = o;
    }
}

// one 64-bit atomicMax per edge: key = (e+1)<<22 | rel<<16 | src
__global__ void k_scatter(const int* __restrict__ edges, u64* __restrict__ packed) {
    int e = blockIdx.x * blockDim.x + threadIdx.x;
    if (e < NE) {
        int s = edges[e * 3 + 0];
        int r = edges[e * 3 + 1];
        int d = edges[e * 3 + 2];
        u64 key = ((u64)(e + 1) << 22) | ((u64)r << 16) | (u64)s;
        atomicMax(&packed[d], key);
    }
}

// block-aggregated bucket fill: LDS histogram -> 1 global atomic per (block, rel)
__global__ __launch_bounds__(256) void k_fill(
    const u64* __restrict__ packed, int* __restrict__ cursor,
    unsigned* __restrict__ rbucket, unsigned* __restrict__ sbucket)
{
    __shared__ int hcnt[65];
    __shared__ int hbase[65];
    const int t = threadIdx.x;
    if (t < 65) hcnt[t] = 0;
    __syncthreads();

    int      myr[FILL_ITERS];
    int      myslot[FILL_ITERS];
    unsigned myent[FILL_ITERS];

    #pragma unroll
    for (int it = 0; it < FILL_ITERS; ++it) {
        const int v = (blockIdx.x * FILL_ITERS + it) * 256 + t;
        myr[it] = -1;
        if (v < NN) {
            u64 key = packed[v];
            if (key) {
                myr[it]   = (int)((key >> 16) & 63);
                myent[it] = ((unsigned)v << 16) | (unsigned)(key & 0xFFFF);
            } else {
                myr[it]   = 64;
                myent[it] = (unsigned)v;
            }
            myslot[it] = atomicAdd(&hcnt[myr[it]], 1);
        }
    }
    __syncthreads();
    if (t < 65 && hcnt[t] > 0)
        hbase[t] = atomicAdd(&cursor[t * CSTR], hcnt[t]);
    __syncthreads();

    #pragma unroll
    for (int it = 0; it < FILL_ITERS; ++it) {
        const int r = myr[it];
        if (r >= 0) {
            const int p = hbase[r] + myslot[it];
            if (r < 64) { if (p < RCAP) rbucket[r * RCAP + p] = myent[it]; }
            else        { if (p < SCAP) sbucket[p] = myent[it]; }
        }
    }
}

// MFMA compute: A = W^T frags (loop-invariant, direct 16B loads), B = gathered
// h rows. C: row=(l>>4)*4+q = output dim, col=l&15 = node -> each lane stores
// its own node's float4 (no shfl, no LDS). Verified r17 (absmax 0.0625).
__global__ __launch_bounds__(256) void k_compute(
    const _Float16* __restrict__ h2, const _Float16* __restrict__ w16T,
    const _Float16* __restrict__ wsT, const unsigned* __restrict__ rbucket,
    const unsigned* __restrict__ sbucket, const int* __restrict__ cursor,
    float* __restrict__ out)
{
    const int lane = threadIdx.x & 63;
    const int wv   = threadIdx.x >> 6;
    const bool isRel = blockIdx.x < NREL * BR;

    int r = 64, wslot, wstride, cnt;
    const unsigned* __restrict__ seg;
    if (isRel) {
        r = blockIdx.x / BR;
        wslot = (blockIdx.x % BR) * 4 + wv;
        wstride = BR * 4;
        seg = rbucket + r * RCAP;
        cnt = min(cursor[r * CSTR], RCAP);
    } else {
        wslot = (blockIdx.x - NREL * BR) * 4 + wv;
        wstride = SBLK * 4;
        seg = sbucket;
        cnt = min(cursor[64 * CSTR], SCAP);
    }
    if (cnt == 0 || wslot * 16 >= cnt) return;

    const int kbase = (lane >> 4) * 8;
    const int ncol  = lane & 15;            // A-row (output-dim sub) / B-col (node)

    f16x8 was[4][2];
    #pragma unroll
    for (int nt = 0; nt < 4; ++nt)
        #pragma unroll
        for (int ks = 0; ks < 2; ++ks)
            was[nt][ks] = *reinterpret_cast<const f16x8*>(
                wsT + (size_t)(nt * 16 + ncol) * D + ks * 32 + kbase);

    f16x8 wa[4][2];
    if (isRel) {
        const _Float16* __restrict__ wr = w16T + ((size_t)r << 12);
        #pragma unroll
        for (int nt = 0; nt < 4; ++nt)
            #pragma unroll
            for (int ks = 0; ks < 2; ++ks)
                wa[nt][ks] = *reinterpret_cast<const f16x8*>(
                    wr + (size_t)(nt * 16 + ncol) * D + ks * 32 + kbase);
    }

    for (int tt = wslot; tt * 16 < cnt; tt += wstride) {
        const unsigned ent = seg[min(tt * 16 + ncol, cnt - 1)];  // this lane's node
        const int v = isRel ? (int)(ent >> 16) : (int)ent;
        const int s = (int)(ent & 0xFFFF);

        f32x4 c[4];
        #pragma unroll
        for (int nt = 0; nt < 4; ++nt) c[nt] = (f32x4){0.f, 0.f, 0.f, 0.f};

        {   // self part: B = h2[v]
            const f16x8 b0 = *reinterpret_cast<const f16x8*>(h2 + (size_t)v * D + kbase);
            const f16x8 b1 = *reinterpret_cast<const f16x8*>(h2 + (size_t)v * D + 32 + kbase);
            #pragma unroll
            for (int nt = 0; nt < 4; ++nt) {
                c[nt] = __builtin_amdgcn_mfma_f32_16x16x32_f16(was[nt][0], b0, c[nt], 0, 0, 0);
                c[nt] = __builtin_amdgcn_mfma_f32_16x16x32_f16(was[nt][1], b1, c[nt], 0, 0, 0);
            }
        }
        if (isRel) {   // rel part: B = h2[s]
            const f16x8 b0 = *reinterpret_cast<const f16x8*>(h2 + (size_t)s * D + kbase);
            const f16x8 b1 = *reinterpret_cast<const f16x8*>(h2 + (size_t)s * D + 32 + kbase);
            #pragma unroll
            for (int nt = 0; nt < 4; ++nt) {
                c[nt] = __builtin_amdgcn_mfma_f32_16x16x32_f16(wa[nt][0], b0, c[nt], 0, 0, 0);
                c[nt] = __builtin_amdgcn_mfma_f32_16x16x32_f16(wa[nt][1], b1, c[nt], 0, 0, 0);
            }
        }

        // store: lane's node v, output dims o = nt*16 + (lane>>4)*4 + q
        float* __restrict__ orow = out + (size_t)v * D + (lane >> 4) * 4;
        #pragma unroll
        for (int nt = 0; nt < 4; ++nt)
            *reinterpret_cast<float4*>(orow + nt * 16) =
                make_float4(c[nt][0], c[nt][1], c[nt][2], c[nt][3]);
    }
}

extern "C" void kernel_launch(void* const* d_in, const int* in_sizes, int n_in,
                              void* d_out, int out_size, void* d_ws, size_t ws_size,
                              hipStream_t stream) {
    const float* h      = (const float*)d_in[0];
    const int*   edges  = (const int*)d_in[1];
    const float* weight = (const float*)d_in[2];
    const float* wself  = (const float*)d_in[3];
    float* out = (float*)d_out;

    char* ws = (char*)d_ws;
    u64*      packed  = (u64*)ws;
    int*      cursor  = (int*)(ws + WS_CURSOR);
    unsigned* rbucket = (unsigned*)(ws + WS_RBUCKET);
    unsigned* sbucket = (unsigned*)(ws + WS_SBUCKET);
    _Float16* h2      = (_Float16*)(ws + WS_H2);
    _Float16* wsT     = (_Float16*)(ws + WS_WST);
    _Float16* w16T    = (_Float16*)(ws + WS_W16T);

    k_pre<<<PRE_BLOCKS, 256, 0, stream>>>(h, weight, wself, packed, cursor, h2, w16T, wsT);
    k_scatter<<<(NE + 255) / 256, 256, 0, stream>>>(edges, packed);
    k_fill<<<FILL_BLOCKS, 256, 0, stream>>>(packed, cursor, rbucket, sbucket);
    k_compute<<<NREL * BR + SBLK, 256, 0, stream>>>(h2, w16T, wsT, rbucket, sbucket, cursor, out);
}

// Round 20
// 34.538 us; speedup vs baseline: 5.4421x; 1.0257x over previous
//
#include <hip/hip_runtime.h>

#define NN 50000
#define NE 100000
#define NREL 64
#define D 64
#define RCAP 1280      // per-relation bucket capacity (expected ~676)
#define SCAP 8192      // self-only bucket capacity (expected ~6766)
#define CSTR 16        // cursor stride in ints (64 B per counter)
#define BR   12        // rel blocks per relation (48 waves/rel ~= 1 tile/wave)
#define SBLK 64        // self-only blocks
#define FILL_BLOCKS 128
#define FILL_ITERS  2
#define SC_BLK ((NE + 255) / 256)   // 391 scatter blocks
#define TR_BLK 65                   // weight-transpose blocks

typedef unsigned long long u64;
using f16x8 = __attribute__((ext_vector_type(8))) _Float16;
using f32x4 = __attribute__((ext_vector_type(4))) float;

// ws layout (bytes):
// packed @0 (400KB) | cursor @400K | rbucket @408K (327.7KB) | sbucket @736K (32KB) |
// wsT @768K (8KB) | w16T @776K (512KB)
#define WS_CURSOR  (400 * 1024)
#define WS_RBUCKET (408 * 1024)
#define WS_SBUCKET (736 * 1024)
#define WS_WST     (768 * 1024)
#define WS_W16T    (776 * 1024)

// zero packed + cursor (only serial prerequisite of the scatter)
__global__ __launch_bounds__(256) void k_zero(u64* __restrict__ packed, int* __restrict__ cursor) {
    const int gt = blockIdx.x * 256 + threadIdx.x;
    const int nthr = gridDim.x * 256;
    for (int i = gt; i < NN; i += nthr) packed[i] = 0ull;
    if (gt < 65) cursor[gt * CSTR] = 0;
}

// fused: [0,SC_BLK) edge scatter | [SC_BLK,+TR_BLK) weight transpose->f16
__global__ __launch_bounds__(256) void k_scatter(
    const int* __restrict__ edges, const float* __restrict__ weight,
    const float* __restrict__ wself, u64* __restrict__ packed,
    _Float16* __restrict__ w16T, _Float16* __restrict__ wsT)
{
    __shared__ _Float16 tile[D * D];   // 8 KiB

    if (blockIdx.x < SC_BLK) {
        const int e = blockIdx.x * 256 + threadIdx.x;
        if (e < NE) {
            const int s = edges[e * 3 + 0];
            const int r = edges[e * 3 + 1];
            const int d = edges[e * 3 + 2];
            const u64 key = ((u64)(e + 1) << 22) | ((u64)r << 16) | (u64)s;
            atomicMax(&packed[d], key);
        }
        return;
    }

    // transpose one matrix: tile[n][k] = (f16)W[k][n], coalesced f16x8 write-out
    const int r = blockIdx.x - SC_BLK;              // 0..63 rel, 64 = wself
    const int t = threadIdx.x;
    const float4* __restrict__ src4 = reinterpret_cast<const float4*>(
        (r < NREL) ? (weight + (size_t)r * D * D) : wself);
    #pragma unroll
    for (int it = 0; it < 4; ++it) {
        const int idx = it * 256 + t;               // float4 idx 0..1023
        const float4 w = src4[idx];
        const int k  = idx >> 4;
        const int n0 = (idx & 15) << 2;
        tile[(n0 + 0) * D + k] = (_Float16)w.x;
        tile[(n0 + 1) * D + k] = (_Float16)w.y;
        tile[(n0 + 2) * D + k] = (_Float16)w.z;
        tile[(n0 + 3) * D + k] = (_Float16)w.w;
    }
    __syncthreads();
    f16x8* __restrict__ dst = reinterpret_cast<f16x8*>(
        (r < NREL) ? (w16T + ((size_t)r << 12)) : wsT);
    const f16x8* __restrict__ src = reinterpret_cast<const f16x8*>(tile);
    #pragma unroll
    for (int it = 0; it < 2; ++it)
        dst[it * 256 + t] = src[it * 256 + t];
}

// block-aggregated bucket fill: LDS histogram -> 1 global atomic per (block, rel)
__global__ __launch_bounds__(256) void k_fill(
    const u64* __restrict__ packed, int* __restrict__ cursor,
    unsigned* __restrict__ rbucket, unsigned* __restrict__ sbucket)
{
    __shared__ int hcnt[65];
    __shared__ int hbase[65];
    const int t = threadIdx.x;
    if (t < 65) hcnt[t] = 0;
    __syncthreads();

    int      myr[FILL_ITERS];
    int      myslot[FILL_ITERS];
    unsigned myent[FILL_ITERS];

    #pragma unroll
    for (int it = 0; it < FILL_ITERS; ++it) {
        const int v = (blockIdx.x * FILL_ITERS + it) * 256 + t;
        myr[it] = -1;
        if (v < NN) {
            const u64 key = packed[v];
            if (key) {
                myr[it]   = (int)((key >> 16) & 63);
                myent[it] = ((unsigned)v << 16) | (unsigned)(key & 0xFFFF);
            } else {
                myr[it]   = 64;
                myent[it] = (unsigned)v;
            }
            myslot[it] = atomicAdd(&hcnt[myr[it]], 1);
        }
    }
    __syncthreads();
    if (t < 65 && hcnt[t] > 0)
        hbase[t] = atomicAdd(&cursor[t * CSTR], hcnt[t]);
    __syncthreads();

    #pragma unroll
    for (int it = 0; it < FILL_ITERS; ++it) {
        const int r = myr[it];
        if (r >= 0) {
            const int p = hbase[r] + myslot[it];
            if (r < 64) { if (p < RCAP) rbucket[r * RCAP + p] = myent[it]; }
            else        { if (p < SCAP) sbucket[p] = myent[it]; }
        }
    }
}

__device__ __forceinline__ f16x8 cvt_frag(const float* __restrict__ p) {
    const float4 p0 = *reinterpret_cast<const float4*>(p);
    const float4 p1 = *reinterpret_cast<const float4*>(p + 4);
    f16x8 a;
    a[0] = (_Float16)p0.x; a[1] = (_Float16)p0.y; a[2] = (_Float16)p0.z; a[3] = (_Float16)p0.w;
    a[4] = (_Float16)p1.x; a[5] = (_Float16)p1.y; a[6] = (_Float16)p1.z; a[7] = (_Float16)p1.w;
    return a;
}

// MFMA compute (r16 structure): A = gathered h rows (f32 -> f16 in-register),
// B = pre-transposed f16 weights (direct 16B loads, loop-invariant).
// C/D: lane l, reg q -> row m=(l>>4)*4+q (node slot), col n=l&15 (output sub)
__global__ __launch_bounds__(256) void k_compute(
    const float* __restrict__ h, const _Float16* __restrict__ w16T,
    const _Float16* __restrict__ wsT, const unsigned* __restrict__ rbucket,
    const unsigned* __restrict__ sbucket, const int* __restrict__ cursor,
    float* __restrict__ out)
{
    const int lane = threadIdx.x & 63;
    const int wv   = threadIdx.x >> 6;
    const bool isRel = blockIdx.x < NREL * BR;

    int r = 64, wslot, wstride, cnt;
    const unsigned* __restrict__ seg;
    if (isRel) {
        r = blockIdx.x / BR;
        wslot = (blockIdx.x % BR) * 4 + wv;
        wstride = BR * 4;
        seg = rbucket + r * RCAP;
        cnt = min(cursor[r * CSTR], RCAP);
    } else {
        wslot = (blockIdx.x - NREL * BR) * 4 + wv;
        wstride = SBLK * 4;
        seg = sbucket;
        cnt = min(cursor[64 * CSTR], SCAP);
    }
    if (cnt == 0 || wslot * 16 >= cnt) return;

    const int kbase = (lane >> 4) * 8;
    const int ncol  = lane & 15;            // B-col n (output sub) / node slot in tile

    // ---- B-frags: direct 16B loads from transposed f16 weights ----
    f16x8 bws[4][2];
    #pragma unroll
    for (int nt = 0; nt < 4; ++nt)
        #pragma unroll
        for (int ks = 0; ks < 2; ++ks)
            bws[nt][ks] = *reinterpret_cast<const f16x8*>(
                wsT + (size_t)(nt * 16 + ncol) * D + ks * 32 + kbase);

    f16x8 bw[4][2];
    if (isRel) {
        const _Float16* __restrict__ wr = w16T + ((size_t)r << 12);
        #pragma unroll
        for (int nt = 0; nt < 4; ++nt)
            #pragma unroll
            for (int ks = 0; ks < 2; ++ks)
                bw[nt][ks] = *reinterpret_cast<const f16x8*>(
                    wr + (size_t)(nt * 16 + ncol) * D + ks * 32 + kbase);
    }

    // ---- tile loop (typically 1 iteration at BR=12) ----
    for (int t = wslot; t * 16 < cnt; t += wstride) {
        const unsigned ent = seg[min(t * 16 + ncol, cnt - 1)];
        const int v = isRel ? (int)(ent >> 16) : (int)ent;
        const int s = (int)(ent & 0xFFFF);

        // issue ALL gathers up front (f32, converted below)
        const float* __restrict__ hv = h + (size_t)v * D;
        const f16x8 a0 = cvt_frag(hv + kbase);
        const f16x8 a1 = cvt_frag(hv + 32 + kbase);

        f32x4 c[4];
        #pragma unroll
        for (int nt = 0; nt < 4; ++nt) c[nt] = (f32x4){0.f, 0.f, 0.f, 0.f};

        if (isRel) {
            const float* __restrict__ hs = h + (size_t)s * D;
            const f16x8 b0 = cvt_frag(hs + kbase);
            const f16x8 b1 = cvt_frag(hs + 32 + kbase);
            #pragma unroll
            for (int nt = 0; nt < 4; ++nt) {
                c[nt] = __builtin_amdgcn_mfma_f32_16x16x32_f16(a0, bws[nt][0], c[nt], 0, 0, 0);
                c[nt] = __builtin_amdgcn_mfma_f32_16x16x32_f16(a1, bws[nt][1], c[nt], 0, 0, 0);
                c[nt] = __builtin_amdgcn_mfma_f32_16x16x32_f16(b0, bw[nt][0], c[nt], 0, 0, 0);
                c[nt] = __builtin_amdgcn_mfma_f32_16x16x32_f16(b1, bw[nt][1], c[nt], 0, 0, 0);
            }
        } else {
            #pragma unroll
            for (int nt = 0; nt < 4; ++nt) {
                c[nt] = __builtin_amdgcn_mfma_f32_16x16x32_f16(a0, bws[nt][0], c[nt], 0, 0, 0);
                c[nt] = __builtin_amdgcn_mfma_f32_16x16x32_f16(a1, bws[nt][1], c[nt], 0, 0, 0);
            }
        }

        // store: reg q holds row m=(lane>>4)*4+q (node), col = ncol (output sub)
        int vrow[4];
        #pragma unroll
        for (int q = 0; q < 4; ++q)
            vrow[q] = __shfl(v, (lane >> 4) * 4 + q, 64);

        #pragma unroll
        for (int nt = 0; nt < 4; ++nt)
            #pragma unroll
            for (int q = 0; q < 4; ++q)
                out[(size_t)vrow[q] * D + nt * 16 + ncol] = c[nt][q];
    }
}

extern "C" void kernel_launch(void* const* d_in, const int* in_sizes, int n_in,
                              void* d_out, int out_size, void* d_ws, size_t ws_size,
                              hipStream_t stream) {
    const float* h      = (const float*)d_in[0];
    const int*   edges  = (const int*)d_in[1];
    const float* weight = (const float*)d_in[2];
    const float* wself  = (const float*)d_in[3];
    float* out = (float*)d_out;

    char* ws = (char*)d_ws;
    u64*      packed  = (u64*)ws;
    int*      cursor  = (int*)(ws + WS_CURSOR);
    unsigned* rbucket = (unsigned*)(ws + WS_RBUCKET);
    unsigned* sbucket = (unsigned*)(ws + WS_SBUCKET);
    _Float16* wsT     = (_Float16*)(ws + WS_WST);
    _Float16* w16T    = (_Float16*)(ws + WS_W16T);

    k_zero<<<98, 256, 0, stream>>>(packed, cursor);
    k_scatter<<<SC_BLK + TR_BLK, 256, 0, stream>>>(edges, weight, wself, packed, w16T, wsT);
    k_fill<<<FILL_BLOCKS, 256, 0, stream>>>(packed, cursor, rbucket, sbucket);
    k_compute<<<NREL * BR + SBLK, 256, 0, stream>>>(h, w16T, wsT, rbucket, sbucket, cursor, out);
}